// Round 4
// baseline (169.823 us; speedup 1.0000x reference)
//
#include <hip/hip_runtime.h>
#include <stdint.h>

#define BB 8
#define TT 256
#define DD 256
#define NSTEP 12
#define NNEG 100
#define NPART (255 * BB * NSTEP)

typedef _Float16 h2 __attribute__((ext_vector_type(2)));
typedef _Float16 f16x8 __attribute__((ext_vector_type(8)));
typedef float f32x4 __attribute__((ext_vector_type(4)));

#if __has_builtin(__builtin_amdgcn_fdot2)
__device__ __forceinline__ float fdot2(h2 a, h2 b, float c) {
  return __builtin_amdgcn_fdot2(a, b, c, false);
}
#else
__device__ __forceinline__ float fdot2(h2 a, h2 b, float c) {
  return c + (float)a.x * (float)b.x + (float)a.y * (float)b.y;
}
#endif

union V16 { uint4 u; h2 h[4]; };

// ---------------- Threefry2x32 (JAX-compatible), host+device ----------------
__host__ __device__ __forceinline__ void tf2x32(uint32_t k0, uint32_t k1,
                                                uint32_t x0, uint32_t x1,
                                                uint32_t &y0, uint32_t &y1) {
  const uint32_t ks2 = k0 ^ k1 ^ 0x1BD11BDAu;
  x0 += k0; x1 += k1;
#define TF_R(r) { x0 += x1; x1 = (x1 << (r)) | (x1 >> (32 - (r))); x1 ^= x0; }
  TF_R(13) TF_R(15) TF_R(26) TF_R(6)
  x0 += k1; x1 += ks2 + 1u;
  TF_R(17) TF_R(29) TF_R(16) TF_R(24)
  x0 += ks2; x1 += k0 + 2u;
  TF_R(13) TF_R(15) TF_R(26) TF_R(6)
  x0 += k0; x1 += k1 + 3u;
  TF_R(17) TF_R(29) TF_R(16) TF_R(24)
  x0 += k1; x1 += ks2 + 4u;
  TF_R(13) TF_R(15) TF_R(26) TF_R(6)
  x0 += ks2; x1 += k0 + 5u;
#undef TF_R
  y0 = x0; y1 = x1;
}

// ---------------- host-computed per-step constants ----------------
struct IdxParams {
  uint32_t k1x[NSTEP], k1y[NSTEP], k2x[NSTEP], k2y[NSTEP];
  uint32_t mult[NSTEP];
  uint32_t Msp[NSTEP], Ssp[NSTEP], Asp[NSTEP];   // magic for span = 8*T2
  uint32_t Mt2[NSTEP], St2[NSTEP], At2[NSTEP];   // magic for T2
};

// Hacker's Delight 10-9 unsigned magic
static void magicu(uint32_t d, uint32_t* M, uint32_t* s, uint32_t* a) {
  uint32_t p, nc, delta, q1, r1, q2, r2;
  *a = 0;
  nc = 0xFFFFFFFFu - (0u - d) % d;
  p = 31;
  q1 = 0x80000000u / nc; r1 = 0x80000000u - q1 * nc;
  q2 = 0x7FFFFFFFu / d;  r2 = 0x7FFFFFFFu - q2 * d;
  do {
    p = p + 1;
    if (r1 >= nc - r1) { q1 = 2*q1 + 1; r1 = 2*r1 - nc; }
    else               { q1 = 2*q1;     r1 = 2*r1; }
    if (r2 + 1 >= d - r2) {
      if (q2 >= 0x7FFFFFFFu) *a = 1;
      q2 = 2*q2 + 1; r2 = 2*r2 + 1 - d;
    } else {
      if (q2 >= 0x80000000u) *a = 1;
      q2 = 2*q2; r2 = 2*r2 + 1;
    }
    delta = d - 1 - r2;
  } while (p < 64 && (q1 < delta || (q1 == delta && r1 == 0)));
  *M = q2 + 1; *s = p - 32;
}

__device__ __forceinline__ uint32_t mdiv(uint32_t n, uint32_t M, uint32_t s, uint32_t a) {
  uint32_t q = __umulhi(n, M);
  if (a) { q = ((n - q) >> 1) + q; return q >> (s - 1); }
  return q >> s;
}

// ------------- prep: tgt-l2norm->f16, ctx->f16, W->f16 -------------
__global__ __launch_bounds__(256) void prep_kernel(const float* __restrict__ tgt,
                                                   const float* __restrict__ ctx,
                                                   const float* __restrict__ W,
                                                   _Float16* __restrict__ tnh,
                                                   _Float16* __restrict__ ctxh,
                                                   _Float16* __restrict__ Wh) {
  const int bx = blockIdx.x;
  const int tid = threadIdx.x;
  const int lane = tid & 63;
  union { _Float16 h[4]; uint2 u; } o;
  if (bx < 512) {                                        // tgt: normalize
    const int row = bx * 4 + (tid >> 6);
    float4 v = ((const float4*)(tgt + (size_t)row * DD))[lane];
    float ss = v.x*v.x + v.y*v.y + v.z*v.z + v.w*v.w;
#pragma unroll
    for (int off = 1; off < 64; off <<= 1) ss += __shfl_xor(ss, off, 64);
    const float sc = 1.0f / fmaxf(sqrtf(ss), 1e-12f);
    o.h[0] = (_Float16)(v.x * sc); o.h[1] = (_Float16)(v.y * sc);
    o.h[2] = (_Float16)(v.z * sc); o.h[3] = (_Float16)(v.w * sc);
    ((uint2*)(tnh + (size_t)row * DD))[lane] = o.u;
  } else if (bx < 1024) {                                // ctx: plain convert
    const int row = (bx - 512) * 4 + (tid >> 6);
    float4 v = ((const float4*)(ctx + (size_t)row * DD))[lane];
    o.h[0] = (_Float16)v.x; o.h[1] = (_Float16)v.y;
    o.h[2] = (_Float16)v.z; o.h[3] = (_Float16)v.w;
    ((uint2*)(ctxh + (size_t)row * DD))[lane] = o.u;
  } else {                                               // W: plain convert (3072 rows)
    const int row = (bx - 1024) * 4 + (tid >> 6);
    float4 v = ((const float4*)(W + (size_t)row * DD))[lane];
    o.h[0] = (_Float16)v.x; o.h[1] = (_Float16)v.y;
    o.h[2] = (_Float16)v.z; o.h[3] = (_Float16)v.w;
    ((uint2*)(Wh + (size_t)row * DD))[lane] = o.u;
  }
}

// ------------- negative-index generation (threefry + magic-mod) -------------
__global__ __launch_bounds__(256) void idx_gen_kernel(const IdxParams P,
                                                      uint16_t* __restrict__ idx) {
  const int si = blockIdx.z;
  const int b  = blockIdx.y;
  const int lin = blockIdx.x * 256 + threadIdx.x;
  if (lin >= 255 * NNEG) return;
  const int t = lin / NNEG;                    // constant divisor -> compiler magic
  const int step = si + 1;
  const int T2 = TT - step;
  if (t >= T2) return;
  const uint32_t span = (uint32_t)(BB * T2);
  const uint32_t j = (uint32_t)(b * T2 * NNEG + lin);
  uint32_t h0, h1, l0, l1;
  tf2x32(P.k1x[si], P.k1y[si], 0u, j, h0, h1);
  tf2x32(P.k2x[si], P.k2y[si], 0u, j, l0, l1);
  const uint32_t Msp = P.Msp[si], Ssp = P.Ssp[si], Asp = P.Asp[si];
  const uint32_t hm = h0 - mdiv(h0, Msp, Ssp, Asp) * span;
  const uint32_t lm = l0 - mdiv(l0, Msp, Ssp, Asp) * span;
  const uint32_t off = hm * P.mult[si] + lm;   // < ~2^22
  const uint32_t om = off - mdiv(off, Msp, Ssp, Asp) * span;
  const uint32_t bb = mdiv(om, P.Mt2[si], P.St2[si], P.At2[si]);
  const uint32_t tt = om - bb * (uint32_t)T2;
  idx[(size_t)(si * BB + b) * 255 * NNEG + lin] = (uint16_t)(bb * TT + tt + (uint32_t)step);
}

// ------------- query GEMM (MFMA f16) + bias + l2norm -> f16 -------------
__global__ __launch_bounds__(256) void qgemm_mfma_kernel(const _Float16* __restrict__ ctxh,
                                                         const _Float16* __restrict__ Wh,
                                                         const float* __restrict__ bias,
                                                         _Float16* __restrict__ qnh) {
  const int mt  = blockIdx.x;           // 0..127
  const int s   = blockIdx.y;           // 0..11
  const int tid = threadIdx.x;
  const int w   = tid >> 6;             // wave -> n0 = w*64
  const int lane = tid & 63;
  const int sl = lane & 15;
  const int q  = lane >> 4;
  const int m0 = mt * 16;

  const _Float16* Arow  = ctxh + ((size_t)(m0 + sl)) * DD + q * 8;
  const _Float16* Bbase = Wh + (size_t)s * DD * DD + ((size_t)(w * 64 + sl)) * DD + q * 8;

  f32x4 acc[4] = {f32x4{0,0,0,0}, f32x4{0,0,0,0}, f32x4{0,0,0,0}, f32x4{0,0,0,0}};
#pragma unroll
  for (int k0 = 0; k0 < 8; ++k0) {
    const f16x8 a = *(const f16x8*)(Arow + k0 * 32);
#pragma unroll
    for (int nt = 0; nt < 4; ++nt) {
      const f16x8 b = *(const f16x8*)(Bbase + (size_t)nt * 16 * DD + k0 * 32);
      acc[nt] = __builtin_amdgcn_mfma_f32_16x16x32_f16(a, b, acc[nt], 0, 0, 0);
    }
  }
  const float* bp = bias + (size_t)s * DD + w * 64 + sl;
#pragma unroll
  for (int nt = 0; nt < 4; ++nt) {
    const float bv = bp[nt * 16];
#pragma unroll
    for (int r = 0; r < 4; ++r) acc[nt][r] += bv;
  }
  float ss[4];
#pragma unroll
  for (int r = 0; r < 4; ++r) {
    float v = 0.f;
#pragma unroll
    for (int nt = 0; nt < 4; ++nt) v += acc[nt][r] * acc[nt][r];
    ss[r] = v;
  }
#pragma unroll
  for (int off = 1; off < 16; off <<= 1) {
#pragma unroll
    for (int r = 0; r < 4; ++r) ss[r] += __shfl_xor(ss[r], off, 64);
  }
  __shared__ float part[4][16];
  if (sl == 0) {
#pragma unroll
    for (int r = 0; r < 4; ++r) part[w][q * 4 + r] = ss[r];
  }
  __syncthreads();
#pragma unroll
  for (int r = 0; r < 4; ++r) {
    const int row = q * 4 + r;
    const float tot = part[0][row] + part[1][row] + part[2][row] + part[3][row];
    const float sc = 1.0f / fmaxf(sqrtf(tot), 1e-12f);
    _Float16* outp = qnh + (((size_t)s * (BB * TT)) + m0 + row) * DD + w * 64 + sl;
#pragma unroll
    for (int nt = 0; nt < 4; ++nt) outp[nt * 16] = (_Float16)(acc[nt][r] * sc);
  }
}

// ------------- scoring: 4-lane dot groups, q in registers -------------
__global__ __launch_bounds__(128) void score_kernel(const _Float16* __restrict__ qnh,
                                                    const _Float16* __restrict__ tnh,
                                                    const uint16_t* __restrict__ idx,
                                                    float* __restrict__ partial) {
  const int t    = blockIdx.x;            // 0..254
  const int b    = blockIdx.y;
  const int si   = blockIdx.z;
  const int step = si + 1;
  const int T2   = TT - step;
  const int lin  = (si * BB + b) * 255 + t;
  const int tid  = threadIdx.x;
  if (t >= T2) { if (tid == 0) partial[lin] = 0.f; return; }

  __shared__ int   rowIdx[NNEG + 1];
  __shared__ float logit[NNEG + 1];

  if (tid < NNEG) {
    rowIdx[tid + 1] = (int)idx[(size_t)lin * NNEG + tid];
  } else if (tid == NNEG) {
    rowIdx[0] = b * TT + t + step;        // positive row
  }

  const int g  = tid >> 2;                // dot-group 0..31
  const int gl = tid & 3;                 // lane-in-group: 16B sub-chunk
  // preload q: 8 chunks of 8 halves (16 B) at offsets s*64B + gl*16B
  const _Float16* qrow = qnh + (((size_t)si * (BB * TT)) + b * TT + t) * DD;
  V16 qv[8];
#pragma unroll
  for (int s2 = 0; s2 < 8; ++s2) qv[s2].u = *(const uint4*)(qrow + s2 * 32 + gl * 8);
  __syncthreads();

#pragma unroll
  for (int r = 0; r < 4; ++r) {
    const int k = r * 32 + g;
    if (k <= NNEG) {
      const _Float16* p = tnh + (size_t)rowIdx[k] * DD;
      float d0 = 0.f, d1 = 0.f, d2 = 0.f, d3 = 0.f;
#pragma unroll
      for (int s2 = 0; s2 < 8; ++s2) {
        V16 pv; pv.u = *(const uint4*)(p + s2 * 32 + gl * 8);
        d0 = fdot2(qv[s2].h[0], pv.h[0], d0);
        d1 = fdot2(qv[s2].h[1], pv.h[1], d1);
        d2 = fdot2(qv[s2].h[2], pv.h[2], d2);
        d3 = fdot2(qv[s2].h[3], pv.h[3], d3);
      }
      float d = (d0 + d1) + (d2 + d3);
      d += __shfl_xor(d, 1, 64);
      d += __shfl_xor(d, 2, 64);
      if (gl == 0) logit[k] = d * 10.0f;  // 1/TEMP
    }
  }
  __syncthreads();

  if (tid < 64) {
    const int lane = tid;
    const float a = logit[lane];
    const float c = (lane + 64 <= NNEG) ? logit[lane + 64] : -1e30f;
    float m = fmaxf(a, c);
#pragma unroll
    for (int off = 1; off < 64; off <<= 1) m = fmaxf(m, __shfl_xor(m, off, 64));
    float e = __expf(a - m) + ((lane + 64 <= NNEG) ? __expf(c - m) : 0.f);
#pragma unroll
    for (int off = 1; off < 64; off <<= 1) e += __shfl_xor(e, off, 64);
    if (lane == 0) {
      const float lse = m + logf(e);
      partial[lin] = (lse - logit[0]) / (12.0f * (float)(BB * T2));
    }
  }
}

// ---------------- final reduction ----------------
__global__ __launch_bounds__(1024) void final_sum_kernel(const float* __restrict__ partial,
                                                         float* __restrict__ out) {
  __shared__ float wsum[16];
  const int tid = threadIdx.x;
  float s = 0.f;
  const float4* p4 = (const float4*)partial;
  for (int i = tid; i < NPART / 4; i += 1024) {
    const float4 v = p4[i];
    s += v.x + v.y + v.z + v.w;
  }
#pragma unroll
  for (int off = 1; off < 64; off <<= 1) s += __shfl_xor(s, off, 64);
  if ((tid & 63) == 0) wsum[tid >> 6] = s;
  __syncthreads();
  if (tid == 0) {
    float tot = 0.f;
#pragma unroll
    for (int i = 0; i < 16; ++i) tot += wsum[i];
    out[0] = tot;
  }
}

extern "C" void kernel_launch(void* const* d_in, const int* in_sizes, int n_in,
                              void* d_out, int out_size, void* d_ws, size_t ws_size,
                              hipStream_t stream) {
  const float* ctx  = (const float*)d_in[0];
  const float* tgt  = (const float*)d_in[1];
  const float* W    = (const float*)d_in[2];
  const float* bias = (const float*)d_in[3];
  float* out = (float*)d_out;

  _Float16* tnh  = (_Float16*)d_ws;                          // 1 MB
  _Float16* ctxh = tnh + (size_t)BB * TT * DD;               // 1 MB
  _Float16* Wh   = ctxh + (size_t)BB * TT * DD;              // 1.5 MB
  _Float16* qnh  = Wh + (size_t)NSTEP * DD * DD;             // 12.6 MB
  uint16_t* idx  = (uint16_t*)(qnh + (size_t)NSTEP * BB * TT * DD); // 4.9 MB
  float* partial = (float*)(idx + (size_t)NSTEP * BB * 255 * NNEG); // 98 KB

  // host-side per-step constants (deterministic; same every call)
  IdxParams P;
  for (int s = 0; s < NSTEP; ++s) {
    uint32_t a, b;
    tf2x32(0u, 1234u, 0u, (uint32_t)(s + 1), a, b);          // fold_in(key(1234), step)
    uint32_t h1a, h1b, h2a, h2b;
    tf2x32(a, b, 0u, 2u, h1a, h1b);                          // split -> k1
    tf2x32(a, b, 1u, 3u, h2a, h2b);                          // split -> k2
    P.k1x[s] = h1a; P.k1y[s] = h1b; P.k2x[s] = h2a; P.k2y[s] = h2b;
    const uint32_t T2 = (uint32_t)(TT - (s + 1));
    const uint32_t span = 8u * T2;
    uint32_t m = 65536u % span;
    P.mult[s] = (uint32_t)(((uint64_t)m * m) % span);
    magicu(span, &P.Msp[s], &P.Ssp[s], &P.Asp[s]);
    magicu(T2,   &P.Mt2[s], &P.St2[s], &P.At2[s]);
  }

  hipLaunchKernelGGL(idx_gen_kernel, dim3(100, BB, NSTEP), dim3(256), 0, stream, P, idx);
  hipLaunchKernelGGL(prep_kernel, dim3(1792), dim3(256), 0, stream,
                     tgt, ctx, W, tnh, ctxh, Wh);
  hipLaunchKernelGGL(qgemm_mfma_kernel, dim3(128, NSTEP), dim3(256), 0, stream,
                     ctxh, Wh, bias, qnh);
  hipLaunchKernelGGL(score_kernel, dim3(255, BB, NSTEP), dim3(128), 0, stream,
                     qnh, tnh, idx, partial);
  hipLaunchKernelGGL(final_sum_kernel, dim3(1), dim3(1024), 0, stream, partial, out);
}

// Round 5
// 134.620 us; speedup vs baseline: 1.2615x; 1.2615x over previous
//
#include <hip/hip_runtime.h>
#include <stdint.h>

#define BB 8
#define TT 256
#define DD 256
#define NSTEP 12
#define NNEG 100
#define NPART (255 * BB * NSTEP)

typedef _Float16 h2 __attribute__((ext_vector_type(2)));
typedef _Float16 f16x8 __attribute__((ext_vector_type(8)));
typedef float f32x4 __attribute__((ext_vector_type(4)));

#if __has_builtin(__builtin_amdgcn_fdot2)
__device__ __forceinline__ float fdot2(h2 a, h2 b, float c) {
  return __builtin_amdgcn_fdot2(a, b, c, false);
}
#else
__device__ __forceinline__ float fdot2(h2 a, h2 b, float c) {
  return c + (float)a.x * (float)b.x + (float)a.y * (float)b.y;
}
#endif

// e5m2 byte -> f16 is an exact <<8. Expand dword [b3 b2 b1 b0] into two h2:
// lo = (b0,b1) -> bytes [0,b0,0,b1] ; hi = (b2,b3) -> bytes [0,b2,0,b3]
__device__ __forceinline__ h2 e5m2_lo(uint32_t w) {
#if __has_builtin(__builtin_amdgcn_perm)
  uint32_t r = __builtin_amdgcn_perm(0u, w, 0x010c000cu);
#else
  uint32_t r = ((w & 0xFFu) << 8) | ((w & 0xFF00u) << 16);
#endif
  union { uint32_t u; h2 h; } c; c.u = r; return c.h;
}
__device__ __forceinline__ h2 e5m2_hi(uint32_t w) {
#if __has_builtin(__builtin_amdgcn_perm)
  uint32_t r = __builtin_amdgcn_perm(0u, w, 0x030c020cu);
#else
  uint32_t r = ((w >> 8) & 0xFF00u) | ((w >> 16) & 0xFF000000u) | (((w >> 16) & 0xFFu) << 8);
#endif
  union { uint32_t u; h2 h; } c; c.u = r; return c.h;
}

// f32 -> e5m2 byte with RNE (values |x|<=1, no overflow concerns)
__device__ __forceinline__ uint32_t f32_to_e5m2(float f) {
  union { _Float16 h; uint16_t u; } c; c.h = (_Float16)f;
  uint16_t h = c.u;
  return (uint32_t)((uint16_t)(h + (uint16_t)0x7F + (uint16_t)((h >> 8) & 1u)) >> 8) & 0xFFu;
}

// ---------------- Threefry2x32 (JAX-compatible), host+device ----------------
__host__ __device__ __forceinline__ void tf2x32(uint32_t k0, uint32_t k1,
                                                uint32_t x0, uint32_t x1,
                                                uint32_t &y0, uint32_t &y1) {
  const uint32_t ks2 = k0 ^ k1 ^ 0x1BD11BDAu;
  x0 += k0; x1 += k1;
#define TF_R(r) { x0 += x1; x1 = (x1 << (r)) | (x1 >> (32 - (r))); x1 ^= x0; }
  TF_R(13) TF_R(15) TF_R(26) TF_R(6)
  x0 += k1; x1 += ks2 + 1u;
  TF_R(17) TF_R(29) TF_R(16) TF_R(24)
  x0 += ks2; x1 += k0 + 2u;
  TF_R(13) TF_R(15) TF_R(26) TF_R(6)
  x0 += k0; x1 += k1 + 3u;
  TF_R(17) TF_R(29) TF_R(16) TF_R(24)
  x0 += k1; x1 += ks2 + 4u;
  TF_R(13) TF_R(15) TF_R(26) TF_R(6)
  x0 += ks2; x1 += k0 + 5u;
#undef TF_R
  y0 = x0; y1 = x1;
}

// ---------------- host-computed per-step constants ----------------
struct IdxParams {
  uint32_t k1x[NSTEP], k1y[NSTEP], k2x[NSTEP], k2y[NSTEP];
  uint32_t mult[NSTEP];
  uint32_t Msp[NSTEP], Ssp[NSTEP], Asp[NSTEP];   // magic for span = 8*T2
  uint32_t Mt2[NSTEP], St2[NSTEP], At2[NSTEP];   // magic for T2
};

// Hacker's Delight 10-9 unsigned magic
static void magicu(uint32_t d, uint32_t* M, uint32_t* s, uint32_t* a) {
  uint32_t p, nc, delta, q1, r1, q2, r2;
  *a = 0;
  nc = 0xFFFFFFFFu - (0u - d) % d;
  p = 31;
  q1 = 0x80000000u / nc; r1 = 0x80000000u - q1 * nc;
  q2 = 0x7FFFFFFFu / d;  r2 = 0x7FFFFFFFu - q2 * d;
  do {
    p = p + 1;
    if (r1 >= nc - r1) { q1 = 2*q1 + 1; r1 = 2*r1 - nc; }
    else               { q1 = 2*q1;     r1 = 2*r1; }
    if (r2 + 1 >= d - r2) {
      if (q2 >= 0x7FFFFFFFu) *a = 1;
      q2 = 2*q2 + 1; r2 = 2*r2 + 1 - d;
    } else {
      if (q2 >= 0x80000000u) *a = 1;
      q2 = 2*q2; r2 = 2*r2 + 1;
    }
    delta = d - 1 - r2;
  } while (p < 64 && (q1 < delta || (q1 == delta && r1 == 0)));
  *M = q2 + 1; *s = p - 32;
}

__device__ __forceinline__ uint32_t mdiv(uint32_t n, uint32_t M, uint32_t s, uint32_t a) {
  uint32_t q = __umulhi(n, M);
  if (a) { q = ((n - q) >> 1) + q; return q >> (s - 1); }
  return q >> s;
}

// ------------- prep: tgt-l2norm->e5m2, ctx->f16, W->f16 -------------
__global__ __launch_bounds__(256) void prep_kernel(const float* __restrict__ tgt,
                                                   const float* __restrict__ ctx,
                                                   const float* __restrict__ W,
                                                   uint8_t* __restrict__ tn8,
                                                   _Float16* __restrict__ ctxh,
                                                   _Float16* __restrict__ Wh) {
  const int bx = blockIdx.x;
  const int tid = threadIdx.x;
  const int lane = tid & 63;
  if (bx < 512) {                                        // tgt: normalize -> e5m2
    const int row = bx * 4 + (tid >> 6);
    float4 v = ((const float4*)(tgt + (size_t)row * DD))[lane];
    float ss = v.x*v.x + v.y*v.y + v.z*v.z + v.w*v.w;
#pragma unroll
    for (int off = 1; off < 64; off <<= 1) ss += __shfl_xor(ss, off, 64);
    const float sc = 1.0f / fmaxf(sqrtf(ss), 1e-12f);
    const uint32_t p = f32_to_e5m2(v.x * sc) | (f32_to_e5m2(v.y * sc) << 8)
                     | (f32_to_e5m2(v.z * sc) << 16) | (f32_to_e5m2(v.w * sc) << 24);
    ((uint32_t*)(tn8 + (size_t)row * DD))[lane] = p;
  } else {
    union { _Float16 h[4]; uint2 u; } o;
    if (bx < 1024) {                                     // ctx: plain convert
      const int row = (bx - 512) * 4 + (tid >> 6);
      float4 v = ((const float4*)(ctx + (size_t)row * DD))[lane];
      o.h[0] = (_Float16)v.x; o.h[1] = (_Float16)v.y;
      o.h[2] = (_Float16)v.z; o.h[3] = (_Float16)v.w;
      ((uint2*)(ctxh + (size_t)row * DD))[lane] = o.u;
    } else {                                             // W: plain convert (3072 rows)
      const int row = (bx - 1024) * 4 + (tid >> 6);
      float4 v = ((const float4*)(W + (size_t)row * DD))[lane];
      o.h[0] = (_Float16)v.x; o.h[1] = (_Float16)v.y;
      o.h[2] = (_Float16)v.z; o.h[3] = (_Float16)v.w;
      ((uint2*)(Wh + (size_t)row * DD))[lane] = o.u;
    }
  }
}

// ------------- query GEMM (MFMA f16) + bias + l2norm -> f16 -------------
// grid (64 m-tiles of 32 rows, 12 steps), block 256 = 4 waves.
// wave w owns cols [w*64,(w+1)*64); each B-frag feeds 2 m-tiles (reuse x2).
__global__ __launch_bounds__(256) void qgemm_mfma_kernel(const _Float16* __restrict__ ctxh,
                                                         const _Float16* __restrict__ Wh,
                                                         const float* __restrict__ bias,
                                                         _Float16* __restrict__ qnh) {
  const int mt  = blockIdx.x;           // 0..63
  const int s   = blockIdx.y;           // 0..11
  const int tid = threadIdx.x;
  const int w   = tid >> 6;
  const int lane = tid & 63;
  const int sl = lane & 15;
  const int q  = lane >> 4;
  const int m0 = mt * 32;

  const _Float16* Arow0 = ctxh + ((size_t)(m0 + sl)) * DD + q * 8;
  const _Float16* Arow1 = Arow0 + (size_t)16 * DD;
  const _Float16* Bbase = Wh + (size_t)s * DD * DD + ((size_t)(w * 64 + sl)) * DD + q * 8;

  f32x4 acc[2][4];
#pragma unroll
  for (int mi = 0; mi < 2; ++mi)
#pragma unroll
    for (int nt = 0; nt < 4; ++nt) acc[mi][nt] = f32x4{0, 0, 0, 0};

#pragma unroll
  for (int k0 = 0; k0 < 8; ++k0) {
    const f16x8 a0 = *(const f16x8*)(Arow0 + k0 * 32);
    const f16x8 a1 = *(const f16x8*)(Arow1 + k0 * 32);
#pragma unroll
    for (int nt = 0; nt < 4; ++nt) {
      const f16x8 b = *(const f16x8*)(Bbase + (size_t)nt * 16 * DD + k0 * 32);
      acc[0][nt] = __builtin_amdgcn_mfma_f32_16x16x32_f16(a0, b, acc[0][nt], 0, 0, 0);
      acc[1][nt] = __builtin_amdgcn_mfma_f32_16x16x32_f16(a1, b, acc[1][nt], 0, 0, 0);
    }
  }
  const float* bp = bias + (size_t)s * DD + w * 64 + sl;
  __shared__ float part[4][32];
#pragma unroll
  for (int mi = 0; mi < 2; ++mi) {
#pragma unroll
    for (int nt = 0; nt < 4; ++nt) {
      const float bv = bp[nt * 16];
#pragma unroll
      for (int r = 0; r < 4; ++r) acc[mi][nt][r] += bv;
    }
    float ss[4];
#pragma unroll
    for (int r = 0; r < 4; ++r) {
      float v = 0.f;
#pragma unroll
      for (int nt = 0; nt < 4; ++nt) v += acc[mi][nt][r] * acc[mi][nt][r];
      ss[r] = v;
    }
#pragma unroll
    for (int off = 1; off < 16; off <<= 1) {
#pragma unroll
      for (int r = 0; r < 4; ++r) ss[r] += __shfl_xor(ss[r], off, 64);
    }
    if (sl == 0) {
#pragma unroll
      for (int r = 0; r < 4; ++r) part[w][mi * 16 + q * 4 + r] = ss[r];
    }
  }
  __syncthreads();
#pragma unroll
  for (int mi = 0; mi < 2; ++mi) {
#pragma unroll
    for (int r = 0; r < 4; ++r) {
      const int row = q * 4 + r;
      const float tot = part[0][mi * 16 + row] + part[1][mi * 16 + row]
                      + part[2][mi * 16 + row] + part[3][mi * 16 + row];
      const float sc = 1.0f / fmaxf(sqrtf(tot), 1e-12f);
      _Float16* outp = qnh + (((size_t)s * (BB * TT)) + m0 + mi * 16 + row) * DD + w * 64 + sl;
#pragma unroll
      for (int nt = 0; nt < 4; ++nt) outp[nt * 16] = (_Float16)(acc[mi][nt][r] * sc);
    }
  }
}

// ------------- scoring: inline threefry idx + fp8 gather + log-softmax -------------
__global__ __launch_bounds__(128) void score_kernel(const IdxParams P,
                                                    const _Float16* __restrict__ qnh,
                                                    const uint8_t* __restrict__ tn8,
                                                    float* __restrict__ partial) {
  const int t    = blockIdx.x;            // 0..254
  const int b    = blockIdx.y;
  const int si   = blockIdx.z;
  const int step = si + 1;
  const int T2   = TT - step;
  const int lin  = (si * BB + b) * 255 + t;
  const int tid  = threadIdx.x;
  if (t >= T2) { if (tid == 0) partial[lin] = 0.f; return; }

  __shared__ int   rowIdx[NNEG + 1];
  __shared__ float logit[NNEG + 1];

  if (tid < NNEG) {
    const uint32_t span = (uint32_t)(BB * T2);
    const uint32_t j = (uint32_t)((b * T2 + t) * NNEG + tid);
    uint32_t h0, h1, l0, l1;
    tf2x32(P.k1x[si], P.k1y[si], 0u, j, h0, h1);
    tf2x32(P.k2x[si], P.k2y[si], 0u, j, l0, l1);
    const uint32_t Msp = P.Msp[si], Ssp = P.Ssp[si], Asp = P.Asp[si];
    const uint32_t hm = h0 - mdiv(h0, Msp, Ssp, Asp) * span;
    const uint32_t lm = l0 - mdiv(l0, Msp, Ssp, Asp) * span;
    const uint32_t off = hm * P.mult[si] + lm;
    const uint32_t om = off - mdiv(off, Msp, Ssp, Asp) * span;
    const uint32_t bb = mdiv(om, P.Mt2[si], P.St2[si], P.At2[si]);
    const uint32_t tt = om - bb * (uint32_t)T2;
    rowIdx[tid + 1] = (int)(bb * TT + tt + (uint32_t)step);
  } else if (tid == NNEG) {
    rowIdx[0] = b * TT + t + step;        // positive row
  }

  const int g  = tid >> 2;                // dot-group 0..31
  const int gl = tid & 3;                 // lane-in-group
  // preload q: 8 uint4 (f16), positions chunk c (64 elems) x lane gl (16 elems)
  const _Float16* qrow = qnh + (((size_t)si * (BB * TT)) + b * TT + t) * DD;
  uint4 qv[8];
#pragma unroll
  for (int c = 0; c < 4; ++c) {
    qv[c * 2]     = *(const uint4*)(qrow + c * 64 + gl * 16);
    qv[c * 2 + 1] = *(const uint4*)(qrow + c * 64 + gl * 16 + 8);
  }
  __syncthreads();

#pragma unroll
  for (int r = 0; r < 4; ++r) {
    const int k = r * 32 + g;
    if (k <= NNEG) {
      const uint8_t* prow = tn8 + (size_t)rowIdx[k] * DD;
      float d0 = 0.f, d1 = 0.f, d2 = 0.f, d3 = 0.f;
#pragma unroll
      for (int c = 0; c < 4; ++c) {
        const uint4 pv = *(const uint4*)(prow + c * 64 + gl * 16);
        union { uint4 u; h2 h[4]; } qa, qb;
        qa.u = qv[c * 2]; qb.u = qv[c * 2 + 1];
        d0 = fdot2(qa.h[0], e5m2_lo(pv.x), d0);
        d1 = fdot2(qa.h[1], e5m2_hi(pv.x), d1);
        d2 = fdot2(qa.h[2], e5m2_lo(pv.y), d2);
        d3 = fdot2(qa.h[3], e5m2_hi(pv.y), d3);
        d0 = fdot2(qb.h[0], e5m2_lo(pv.z), d0);
        d1 = fdot2(qb.h[1], e5m2_hi(pv.z), d1);
        d2 = fdot2(qb.h[2], e5m2_lo(pv.w), d2);
        d3 = fdot2(qb.h[3], e5m2_hi(pv.w), d3);
      }
      float d = (d0 + d1) + (d2 + d3);
      d += __shfl_xor(d, 1, 64);
      d += __shfl_xor(d, 2, 64);
      if (gl == 0) logit[k] = d * 10.0f;  // 1/TEMP
    }
  }
  __syncthreads();

  if (tid < 64) {
    const int lane = tid;
    const float a = logit[lane];
    const float c = (lane + 64 <= NNEG) ? logit[lane + 64] : -1e30f;
    float m = fmaxf(a, c);
#pragma unroll
    for (int off = 1; off < 64; off <<= 1) m = fmaxf(m, __shfl_xor(m, off, 64));
    float e = __expf(a - m) + ((lane + 64 <= NNEG) ? __expf(c - m) : 0.f);
#pragma unroll
    for (int off = 1; off < 64; off <<= 1) e += __shfl_xor(e, off, 64);
    if (lane == 0) {
      const float lse = m + logf(e);
      partial[lin] = (lse - logit[0]) / (12.0f * (float)(BB * T2));
    }
  }
}

// ---------------- final reduction ----------------
__global__ __launch_bounds__(1024) void final_sum_kernel(const float* __restrict__ partial,
                                                         float* __restrict__ out) {
  __shared__ float wsum[16];
  const int tid = threadIdx.x;
  float s = 0.f;
  const float4* p4 = (const float4*)partial;
  for (int i = tid; i < NPART / 4; i += 1024) {
    const float4 v = p4[i];
    s += v.x + v.y + v.z + v.w;
  }
#pragma unroll
  for (int off = 1; off < 64; off <<= 1) s += __shfl_xor(s, off, 64);
  if ((tid & 63) == 0) wsum[tid >> 6] = s;
  __syncthreads();
  if (tid == 0) {
    float tot = 0.f;
#pragma unroll
    for (int i = 0; i < 16; ++i) tot += wsum[i];
    out[0] = tot;
  }
}

extern "C" void kernel_launch(void* const* d_in, const int* in_sizes, int n_in,
                              void* d_out, int out_size, void* d_ws, size_t ws_size,
                              hipStream_t stream) {
  const float* ctx  = (const float*)d_in[0];
  const float* tgt  = (const float*)d_in[1];
  const float* W    = (const float*)d_in[2];
  const float* bias = (const float*)d_in[3];
  float* out = (float*)d_out;

  uint8_t* tn8   = (uint8_t*)d_ws;                           // 512 KB
  _Float16* ctxh = (_Float16*)(tn8 + (size_t)BB * TT * DD);  // 1 MB
  _Float16* Wh   = ctxh + (size_t)BB * TT * DD;              // 1.5 MB
  _Float16* qnh  = Wh + (size_t)NSTEP * DD * DD;             // 12.6 MB
  float* partial = (float*)(qnh + (size_t)NSTEP * BB * TT * DD); // 98 KB

  // host-side per-step constants (deterministic; same every call)
  IdxParams P;
  for (int s = 0; s < NSTEP; ++s) {
    uint32_t a, b;
    tf2x32(0u, 1234u, 0u, (uint32_t)(s + 1), a, b);          // fold_in(key(1234), step)
    uint32_t h1a, h1b, h2a, h2b;
    tf2x32(a, b, 0u, 2u, h1a, h1b);                          // split -> k1
    tf2x32(a, b, 1u, 3u, h2a, h2b);                          // split -> k2
    P.k1x[s] = h1a; P.k1y[s] = h1b; P.k2x[s] = h2a; P.k2y[s] = h2b;
    const uint32_t T2 = (uint32_t)(TT - (s + 1));
    const uint32_t span = 8u * T2;
    uint32_t m = 65536u % span;
    P.mult[s] = (uint32_t)(((uint64_t)m * m) % span);
    magicu(span, &P.Msp[s], &P.Ssp[s], &P.Asp[s]);
    magicu(T2,   &P.Mt2[s], &P.St2[s], &P.At2[s]);
  }

  hipLaunchKernelGGL(prep_kernel, dim3(1792), dim3(256), 0, stream,
                     tgt, ctx, W, tn8, ctxh, Wh);
  hipLaunchKernelGGL(qgemm_mfma_kernel, dim3(64, NSTEP), dim3(256), 0, stream,
                     ctxh, Wh, bias, qnh);
  hipLaunchKernelGGL(score_kernel, dim3(255, BB, NSTEP), dim3(128), 0, stream,
                     P, qnh, tn8, partial);
  hipLaunchKernelGGL(final_sum_kernel, dim3(1), dim3(1024), 0, stream, partial, out);
}